// Round 1
// baseline (1883.706 us; speedup 1.0000x reference)
//
#include <hip/hip_runtime.h>

#define FDIM 128
#define HDIM 32
#define BN_EPS 1e-5f

// ---------- degree / norm ----------
__global__ void k_deg_init(float* __restrict__ deg, int n) {
    int i = blockIdx.x * blockDim.x + threadIdx.x;
    if (i < n) deg[i] = 1.0f;  // self-loop
}

__global__ void k_deg_count(const int* __restrict__ col, float* __restrict__ deg, int E) {
    int e = blockIdx.x * blockDim.x + threadIdx.x;
    if (e < E) atomicAdd(&deg[col[e]], 1.0f);
}

__global__ void k_dinv(float* __restrict__ deg, int n) {
    int i = blockIdx.x * blockDim.x + threadIdx.x;
    if (i < n) deg[i] = rsqrtf(deg[i]);  // deg >= 1 always (self-loops)
}

// ---------- small GEMM: Y[n,32] = X[n,K] @ W[K,32] ----------
template <int K>
__global__ void k_gemm(const float* __restrict__ X, const float* __restrict__ W,
                       float* __restrict__ Y, int n) {
    __shared__ __align__(16) float Ws[K * HDIM];
    __shared__ __align__(16) float Xs[8 * K];
    const int tid = threadIdx.x;
    const int row0 = blockIdx.x * 8;

    // stage W (K*32 floats) via float4
    for (int i = tid * 4; i < K * HDIM; i += 256 * 4) {
        *(float4*)&Ws[i] = *(const float4*)&W[i];
    }
    // stage 8 rows of X
    for (int i = tid * 4; i < 8 * K; i += 256 * 4) {
        int r = i / K, k = i % K;
        int gr = row0 + r;
        float4 v = make_float4(0.f, 0.f, 0.f, 0.f);
        if (gr < n) v = *(const float4*)&X[(size_t)gr * K + k];
        *(float4*)&Xs[i] = v;
    }
    __syncthreads();

    const int r = tid >> 5;      // 0..7
    const int c = tid & 31;      // 0..31
    const int grow = row0 + r;
    if (grow < n) {
        float acc = 0.f;
#pragma unroll
        for (int k = 0; k < K; ++k) acc += Xs[r * K + k] * Ws[k * HDIM + c];
        Y[(size_t)grow * HDIM + c] = acc;
    }
}

// ---------- aggregate init: agg[i][j] = dinv[i]^2 * h[i][j] + b[j] ----------
__global__ void k_agg_init(const float* __restrict__ h, const float* __restrict__ dinv,
                           const float* __restrict__ b, float* __restrict__ agg, int n) {
    int i = blockIdx.x * blockDim.x + threadIdx.x;
    if (i < n * HDIM) {
        int node = i >> 5;
        int j = i & 31;
        float d = dinv[node];
        agg[i] = d * d * h[i] + b[j];
    }
}

// ---------- edge scatter: agg[col] += dinv[row]*dinv[col]*h[row] ----------
__global__ void k_scatter(const float* __restrict__ h, const float* __restrict__ dinv,
                          const int* __restrict__ row, const int* __restrict__ col,
                          float* __restrict__ agg, int E) {
    unsigned int gid = blockIdx.x * 256u + threadIdx.x;
    int e = gid >> 5;
    int lane = gid & 31;
    if (e < E) {
        int r = row[e], c = col[e];
        float nrm = dinv[r] * dinv[c];
        float v = h[(size_t)r * HDIM + lane] * nrm;
        atomicAdd(&agg[(size_t)c * HDIM + lane], v);
    }
}

// ---------- batchnorm stats: per-column sum & sumsq ----------
__global__ void k_bnstats(const float* __restrict__ a, float* __restrict__ stats, int n) {
    float s = 0.f, s2 = 0.f;
    int total = n * HDIM;
    int stride = gridDim.x * blockDim.x;  // multiple of 32 (blockDim=256)
    for (int i = blockIdx.x * blockDim.x + threadIdx.x; i < total; i += stride) {
        float v = a[i];
        s += v;
        s2 += v * v;
    }
    // lanes L and L+32 hold the same column (stride multiple of 32)
    s += __shfl_down(s, 32);
    s2 += __shfl_down(s2, 32);
    __shared__ float ls[4][2][32];
    int wave = threadIdx.x >> 6;
    int lane = threadIdx.x & 63;
    if (lane < 32) {
        ls[wave][0][lane] = s;
        ls[wave][1][lane] = s2;
    }
    __syncthreads();
    if (threadIdx.x < 32) {
        int j = threadIdx.x;
        float a0 = ls[0][0][j] + ls[1][0][j] + ls[2][0][j] + ls[3][0][j];
        atomicAdd(&stats[j], a0);
    } else if (threadIdx.x < 64) {
        int j = threadIdx.x - 32;
        float a1 = ls[0][1][j] + ls[1][1][j] + ls[2][1][j] + ls[3][1][j];
        atomicAdd(&stats[HDIM + j], a1);
    }
}

// ---------- batchnorm apply (+ optional relu) ----------
template <bool RELU>
__global__ void k_bnapply(const float* __restrict__ a, const float* __restrict__ stats,
                          const float* __restrict__ gamma, const float* __restrict__ beta,
                          float* __restrict__ out, int n, float invN) {
    int i = blockIdx.x * blockDim.x + threadIdx.x;
    if (i < n * HDIM) {
        int j = i & 31;
        float mean = stats[j] * invN;
        float var = stats[HDIM + j] * invN - mean * mean;
        float g = gamma[j] * rsqrtf(var + BN_EPS);
        float v = (a[i] - mean) * g + beta[j];
        if (RELU) v = fmaxf(v, 0.f);
        out[i] = v;
    }
}

extern "C" void kernel_launch(void* const* d_in, const int* in_sizes, int n_in,
                              void* d_out, int out_size, void* d_ws, size_t ws_size,
                              hipStream_t stream) {
    const float* x   = (const float*)d_in[0];
    const int*   ei  = (const int*)d_in[1];
    const float* W1  = (const float*)d_in[2];
    const float* b1  = (const float*)d_in[3];
    const float* g1  = (const float*)d_in[4];
    const float* be1 = (const float*)d_in[5];
    const float* W2  = (const float*)d_in[6];
    const float* b2  = (const float*)d_in[7];
    const float* g2  = (const float*)d_in[8];
    const float* be2 = (const float*)d_in[9];

    const int N = in_sizes[0] / FDIM;
    const int E = in_sizes[1] / 2;
    const int* row = ei;       // edge_index[0] = source
    const int* col = ei + E;   // edge_index[1] = target

    float* ws    = (float*)d_ws;
    float* dinv  = ws;                        // N
    float* B1    = dinv + N;                  // N*H   (h = X@W)
    float* B2    = B1 + (size_t)N * HDIM;     // N*H   (aggregate)
    float* B3    = B2 + (size_t)N * HDIM;     // N*H   (post-BN/ReLU)
    float* stats = B3 + (size_t)N * HDIM;     // 2*H

    const int nblk_N   = (N + 255) / 256;
    const int nblk_E   = (E + 255) / 256;
    const int nblk_NH  = (N * HDIM + 255) / 256;
    const int nblk_g   = (N + 7) / 8;
    const unsigned int nblk_sc = ((unsigned int)E * 32u + 255u) / 256u;
    const float invN = 1.0f / (float)N;

    // --- normalization coefficients ---
    k_deg_init<<<nblk_N, 256, 0, stream>>>(dinv, N);
    k_deg_count<<<nblk_E, 256, 0, stream>>>(col, dinv, E);
    k_dinv<<<nblk_N, 256, 0, stream>>>(dinv, N);

    // --- layer 1 ---
    k_gemm<FDIM><<<nblk_g, 256, 0, stream>>>(x, W1, B1, N);
    k_agg_init<<<nblk_NH, 256, 0, stream>>>(B1, dinv, b1, B2, N);
    k_scatter<<<nblk_sc, 256, 0, stream>>>(B1, dinv, row, col, B2, E);
    hipMemsetAsync(stats, 0, 2 * HDIM * sizeof(float), stream);
    k_bnstats<<<1280, 256, 0, stream>>>(B2, stats, N);
    k_bnapply<true><<<nblk_NH, 256, 0, stream>>>(B2, stats, g1, be1, B3, N, invN);

    // --- layer 2 ---
    k_gemm<HDIM><<<nblk_g, 256, 0, stream>>>(B3, W2, B1, N);
    k_agg_init<<<nblk_NH, 256, 0, stream>>>(B1, dinv, b2, B2, N);
    k_scatter<<<nblk_sc, 256, 0, stream>>>(B1, dinv, row, col, B2, E);
    hipMemsetAsync(stats, 0, 2 * HDIM * sizeof(float), stream);
    k_bnstats<<<1280, 256, 0, stream>>>(B2, stats, N);
    k_bnapply<false><<<nblk_NH, 256, 0, stream>>>(B2, stats, g2, be2, (float*)d_out, N, invN);
}

// Round 2
// 1337.962 us; speedup vs baseline: 1.4079x; 1.4079x over previous
//
#include <hip/hip_runtime.h>

#define FDIM 128
#define HDIM 32
#define BN_EPS 1e-5f

// ---------- degree histogram (in-degree over col) ----------
__global__ void k_hist(const int* __restrict__ col, int* __restrict__ counts, int E) {
    int e = blockIdx.x * 256 + threadIdx.x;
    if (e < E) atomicAdd(&counts[col[e]], 1);
}

__global__ void k_dinv(const int* __restrict__ counts, float* __restrict__ dinv, int n) {
    int i = blockIdx.x * 256 + threadIdx.x;
    if (i < n) dinv[i] = rsqrtf((float)(counts[i] + 1));  // +1 self-loop
}

// ---------- exclusive scan of counts -> offsets (3-kernel) ----------
// each block covers 1024 counts
__global__ void k_scan_partial(const int* __restrict__ counts, int* __restrict__ bsum, int n) {
    int base = blockIdx.x * 1024 + threadIdx.x * 4;
    int s = 0;
#pragma unroll
    for (int k = 0; k < 4; ++k) { int i = base + k; if (i < n) s += counts[i]; }
#pragma unroll
    for (int off = 32; off > 0; off >>= 1) s += __shfl_down(s, off);
    __shared__ int wsm[4];
    if ((threadIdx.x & 63) == 0) wsm[threadIdx.x >> 6] = s;
    __syncthreads();
    if (threadIdx.x == 0) bsum[blockIdx.x] = wsm[0] + wsm[1] + wsm[2] + wsm[3];
}

__global__ void k_scan_bsums(int* __restrict__ bsum, int nb, int* __restrict__ off_n, int E) {
    if (threadIdx.x == 0 && blockIdx.x == 0) {
        int acc = 0;
        for (int i = 0; i < nb; ++i) { int v = bsum[i]; bsum[i] = acc; acc += v; }
        *off_n = E;  // offsets[N]
    }
}

__global__ void k_scan_final(const int* __restrict__ counts, const int* __restrict__ bsum,
                             int* __restrict__ offsets, int* __restrict__ cursor, int n) {
    int base = blockIdx.x * 1024 + threadIdx.x * 4;
    int v[4]; int ts = 0;
#pragma unroll
    for (int k = 0; k < 4; ++k) { int i = base + k; v[k] = (i < n) ? counts[i] : 0; ts += v[k]; }
    int lane = threadIdx.x & 63, wv = threadIdx.x >> 6;
    int inc = ts;
#pragma unroll
    for (int off = 1; off < 64; off <<= 1) {
        int t = __shfl_up(inc, off);
        if (lane >= off) inc += t;
    }
    __shared__ int wsum[4];
    if (lane == 63) wsum[wv] = inc;
    __syncthreads();
    int pre = bsum[blockIdx.x];
    for (int w = 0; w < wv; ++w) pre += wsum[w];
    int acc = pre + inc - ts;  // exclusive prefix for this thread's first elem
#pragma unroll
    for (int k = 0; k < 4; ++k) {
        int i = base + k;
        if (i < n) { offsets[i] = acc; cursor[i] = acc; acc += v[k]; }
    }
}

// ---------- CSR fill: srcs grouped by destination ----------
__global__ void k_fill(const int* __restrict__ row, const int* __restrict__ col,
                       int* __restrict__ cursor, int* __restrict__ srcs, int E) {
    int e = blockIdx.x * 256 + threadIdx.x;
    if (e < E) {
        int c = col[e];
        int pos = atomicAdd(&cursor[c], 1);
        srcs[pos] = row[e];
    }
}

// ---------- GEMM: Y[n,32] = dinv[n] * (X[n,K] @ W[K,32]); optional fused BN+ReLU on X ----------
template <int K, bool APPLY_BN>
__global__ void k_gemm(const float* __restrict__ X, const float* __restrict__ W,
                       const float* __restrict__ dinv, float* __restrict__ Y, int n,
                       const float* __restrict__ stats, const float* __restrict__ gamma,
                       const float* __restrict__ beta, float invN) {
    __shared__ __align__(16) float Ws[K * HDIM];
    __shared__ __align__(16) float Xs[8 * K];
    __shared__ float bnsc[K], bnsh[K];
    const int tid = threadIdx.x;
    const int row0 = blockIdx.x * 8;

    if (APPLY_BN) {
        if (tid < K) {
            float mean = stats[tid] * invN;
            float var = stats[K + tid] * invN - mean * mean;
            float sc = gamma[tid] * rsqrtf(var + BN_EPS);
            bnsc[tid] = sc;
            bnsh[tid] = beta[tid] - mean * sc;
        }
        __syncthreads();
    }
    for (int i = tid * 4; i < K * HDIM; i += 1024) {
        *(float4*)&Ws[i] = *(const float4*)&W[i];
    }
    for (int i = tid * 4; i < 8 * K; i += 1024) {
        int r = i / K, k = i % K;
        int gr = row0 + r;
        float4 v = make_float4(0.f, 0.f, 0.f, 0.f);
        if (gr < n) v = *(const float4*)&X[(size_t)gr * K + k];
        if (APPLY_BN) {
            v.x = fmaxf(v.x * bnsc[k]     + bnsh[k],     0.f);
            v.y = fmaxf(v.y * bnsc[k + 1] + bnsh[k + 1], 0.f);
            v.z = fmaxf(v.z * bnsc[k + 2] + bnsh[k + 2], 0.f);
            v.w = fmaxf(v.w * bnsc[k + 3] + bnsh[k + 3], 0.f);
        }
        *(float4*)&Xs[i] = v;
    }
    __syncthreads();
    const int r = tid >> 5, c = tid & 31;
    const int grow = row0 + r;
    if (grow < n) {
        float acc = 0.f;
#pragma unroll
        for (int k = 0; k < K; ++k) acc += Xs[r * K + k] * Ws[k * HDIM + c];
        Y[(size_t)grow * HDIM + c] = dinv[grow] * acc;
    }
}

// ---------- gather-aggregate: agg[n] = dinv[n]*(hp[n] + sum_{e into n} hp[src]) + b
// one wave per node (two halves split the edge list); fused BN-stats accumulation.
__global__ void k_aggregate(const float* __restrict__ hp, const float* __restrict__ dinv,
                            const int* __restrict__ offsets, const int* __restrict__ srcs,
                            const float* __restrict__ bias, float* __restrict__ agg,
                            float* __restrict__ stats, int N) {
    const int tid = threadIdx.x;
    const int lane = tid & 63;
    const int j = lane & 31;
    const int half = lane >> 5;
    const int wid = (blockIdx.x * blockDim.x + tid) >> 6;
    const int nw = (gridDim.x * blockDim.x) >> 6;
    const float bj = bias[j];
    float s = 0.f, s2 = 0.f;

    for (int n = wid; n < N; n += nw) {
        int beg = offsets[n], end = offsets[n + 1];
        float acc = half ? 0.f : hp[(size_t)n * HDIM + j];  // self-loop once
        int e = beg + half;
        for (; e + 6 < end; e += 8) {
            int r0 = srcs[e], r1 = srcs[e + 2], r2 = srcs[e + 4], r3 = srcs[e + 6];
            float v0 = hp[(size_t)r0 * HDIM + j], v1 = hp[(size_t)r1 * HDIM + j];
            float v2 = hp[(size_t)r2 * HDIM + j], v3 = hp[(size_t)r3 * HDIM + j];
            acc += (v0 + v1) + (v2 + v3);
        }
        for (; e < end; e += 2) acc += hp[(size_t)srcs[e] * HDIM + j];
        acc += __shfl_xor(acc, 32);          // combine halves; all 64 lanes now hold total
        float out = dinv[n] * acc + bj;
        if (!half) agg[(size_t)n * HDIM + j] = out;
        s += out;                             // both halves accumulate identical values
        s2 += out * out;                      // -> halve at the end
    }

    __shared__ float ls[4][64], ls2[4][64];
    int w = tid >> 6;
    ls[w][lane] = s;
    ls2[w][lane] = s2;
    __syncthreads();
    if (tid < 32) {
        float t = 0.f;
#pragma unroll
        for (int k = 0; k < 4; ++k) t += ls[k][tid] + ls[k][tid + 32];
        atomicAdd(&stats[tid], 0.5f * t);
    } else if (tid < 64) {
        int jj = tid - 32;
        float t = 0.f;
#pragma unroll
        for (int k = 0; k < 4; ++k) t += ls2[k][jj] + ls2[k][jj + 32];
        atomicAdd(&stats[HDIM + jj], 0.5f * t);
    }
}

// ---------- final batchnorm apply (layer 2, no relu) ----------
__global__ void k_bnapply(const float* __restrict__ a, const float* __restrict__ stats,
                          const float* __restrict__ gamma, const float* __restrict__ beta,
                          float* __restrict__ out, int n, float invN) {
    int i = blockIdx.x * 256 + threadIdx.x;
    if (i < n * HDIM) {
        int j = i & 31;
        float mean = stats[j] * invN;
        float var = stats[HDIM + j] * invN - mean * mean;
        float g = gamma[j] * rsqrtf(var + BN_EPS);
        out[i] = (a[i] - mean) * g + beta[j];
    }
}

extern "C" void kernel_launch(void* const* d_in, const int* in_sizes, int n_in,
                              void* d_out, int out_size, void* d_ws, size_t ws_size,
                              hipStream_t stream) {
    const float* x   = (const float*)d_in[0];
    const int*   ei  = (const int*)d_in[1];
    const float* W1  = (const float*)d_in[2];
    const float* b1  = (const float*)d_in[3];
    const float* g1  = (const float*)d_in[4];
    const float* be1 = (const float*)d_in[5];
    const float* W2  = (const float*)d_in[6];
    const float* b2  = (const float*)d_in[7];
    const float* g2  = (const float*)d_in[8];
    const float* be2 = (const float*)d_in[9];

    const int N = in_sizes[0] / FDIM;
    const int E = in_sizes[1] / 2;
    const int* row = ei;      // source
    const int* col = ei + E;  // target

    // bump allocator, 256B-aligned
    char* p = (char*)d_ws;
    auto alloc = [&](size_t bytes) { char* r = p; p += (bytes + 255) & ~(size_t)255; return r; };
    int*   counts  = (int*)alloc((size_t)N * 4);
    int*   cursor  = (int*)alloc((size_t)N * 4);
    int*   offsets = (int*)alloc((size_t)(N + 1) * 4);
    int*   bsum    = (int*)alloc(4096);
    float* dinv    = (float*)alloc((size_t)N * 4);
    int*   srcs    = (int*)alloc((size_t)E * 4);
    float* B1      = (float*)alloc((size_t)N * HDIM * 4);
    float* B2      = (float*)alloc((size_t)N * HDIM * 4);
    float* stats   = (float*)alloc(512);  // stats1 = [0,64), stats2 = [64,128)

    const float invN = 1.0f / (float)N;
    const int NB = (N + 1023) / 1024;

    hipMemsetAsync(counts, 0, (size_t)N * 4, stream);
    hipMemsetAsync(stats, 0, 512, stream);

    // CSR build (shared by both layers)
    k_hist<<<(E + 255) / 256, 256, 0, stream>>>(col, counts, E);
    k_dinv<<<(N + 255) / 256, 256, 0, stream>>>(counts, dinv, N);
    k_scan_partial<<<NB, 256, 0, stream>>>(counts, bsum, N);
    k_scan_bsums<<<1, 64, 0, stream>>>(bsum, NB, offsets + N, E);
    k_scan_final<<<NB, 256, 0, stream>>>(counts, bsum, offsets, cursor, N);
    k_fill<<<(E + 255) / 256, 256, 0, stream>>>(row, col, cursor, srcs, E);

    // layer 1: h1' = dinv*(x@W1); agg1 = dinv*(h1'+gather)+b1, stats1 fused
    k_gemm<FDIM, false><<<(N + 7) / 8, 256, 0, stream>>>(x, W1, dinv, B1, N,
                                                         nullptr, nullptr, nullptr, 0.f);
    k_aggregate<<<1280, 256, 0, stream>>>(B1, dinv, offsets, srcs, b1, B2, stats, N);

    // layer 2: BN1+ReLU fused into gemm2's X load; h2' = dinv*(relu(bn(agg1))@W2)
    k_gemm<HDIM, true><<<(N + 7) / 8, 256, 0, stream>>>(B2, W2, dinv, B1, N,
                                                        stats, g1, be1, invN);
    k_aggregate<<<1280, 256, 0, stream>>>(B1, dinv, offsets, srcs, b2, B2, stats + 2 * HDIM, N);
    k_bnapply<<<(N * HDIM + 255) / 256, 256, 0, stream>>>(B2, stats + 2 * HDIM, g2, be2,
                                                          (float*)d_out, N, invN);
}